// Round 1
// 577.117 us; speedup vs baseline: 1.0080x; 1.0080x over previous
//
#include <hip/hip_runtime.h>

// Problem constants (from reference setup_inputs): V=512, B=256, L=40.
constexpr int V = 512;
constexpr int B = 256;
constexpr int L = 40;
constexpr int ROWS = B * (L - 1);            // 9984 softmax rows
constexpr int WPB = 4;                        // waves per 256-thread block
constexpr int BLOCKS = 624;
constexpr int TOTAL_WAVES = BLOCKS * WPB;     // 2496
constexpr int ITERS = ROWS / TOTAL_WAVES;     // exactly 4 (2496*4 == 9984)

// TOTAL_WAVES = 2496 = 64 * 39, so for wave w the rows r_k = w + 2496k all
// share t = w % 39 and have b_k = w/39 + 64k. t is wave-invariant => the pers
// branch is loop-invariant and the div/mod happens once.
//
// v2 changes vs previous best (578.7 us):
//  - w is readfirstlane'd into an SGPR: all seq index loads and target-logit
//    loads become scalar (s_load) chains instead of 64-lane vector loads of a
//    uniform address.
//  - target logit is loaded directly (sim[prev,tgt], pers[p0,prev,tgt]) as
//    wave-uniform scalars and combined with the SAME fmaf(w1,p,w0*s) as the
//    vector path => bit-identical result, and the runtime-indexed register
//    array v[k][tgt&7] (scratch-demotion hazard, rule #20) plus the final
//    __shfl per row are gone.

__global__ __launch_bounds__(256)
void nll_main(const int* __restrict__ seq,
              const float* __restrict__ sim,
              const float* __restrict__ pers,
              const float* __restrict__ wts,
              float* __restrict__ partial)
{
    const int lane = threadIdx.x & 63;
    const int wib  = threadIdx.x >> 6;
    // Wave id, forced into an SGPR so every derived index is provably uniform.
    const int w = __builtin_amdgcn_readfirstlane((int)(blockIdx.x * WPB + wib));

    const float w0 = wts[0];
    const float w1 = wts[1];

    const int t  = w % 39;                     // position in [0, 38]
    const int b0 = w / 39;                     // batch base in [0, 64)
    const int base = lane * 8;                 // 8 consecutive f32 per lane

    // Gather all index triples first (scalar loads; seq is 40 KB -> L2-resident).
    int prevI[ITERS], tgtI[ITERS], p0I[ITERS];
    #pragma unroll
    for (int k = 0; k < ITERS; ++k) {
        const int off = (b0 + 64 * k) * L + t;
        prevI[k] = seq[off];
        tgtI[k]  = seq[off + 1];
        p0I[k]   = (t >= 1) ? seq[off - 1] : 0;
    }

    // Target logits via wave-uniform scalar loads. Arithmetic is bit-identical
    // to the vector path's element (fmaf(w1, p, w0*s)).
    float lts[ITERS];
    if (t >= 1) {
        #pragma unroll
        for (int k = 0; k < ITERS; ++k) {
            const float st = sim[(size_t)prevI[k] * V + (size_t)tgtI[k]];
            const float pt = pers[((size_t)p0I[k] * V + (size_t)prevI[k]) * V
                                  + (size_t)tgtI[k]];
            lts[k] = fmaf(w1, pt, w0 * st);
        }
    } else {
        #pragma unroll
        for (int k = 0; k < ITERS; ++k) {
            const float st = sim[(size_t)prevI[k] * V + (size_t)tgtI[k]];
            lts[k] = w0 * st;
        }
    }

    // Issue all row loads (4 rows x 2 float4 each for sim and pers) so the
    // cold-HBM latency of the random pers rows overlaps within the wave.
    float v[ITERS][8];
    if (t >= 1) {
        #pragma unroll
        for (int k = 0; k < ITERS; ++k) {
            const float* srow = sim + (size_t)prevI[k] * V + base;
            const float* prow = pers + ((size_t)p0I[k] * V + (size_t)prevI[k]) * V + base;
            const float4 s0 = *(const float4*)(srow);
            const float4 s1 = *(const float4*)(srow + 4);
            const float4 q0 = *(const float4*)(prow);
            const float4 q1 = *(const float4*)(prow + 4);
            v[k][0] = fmaf(w1, q0.x, w0 * s0.x);
            v[k][1] = fmaf(w1, q0.y, w0 * s0.y);
            v[k][2] = fmaf(w1, q0.z, w0 * s0.z);
            v[k][3] = fmaf(w1, q0.w, w0 * s0.w);
            v[k][4] = fmaf(w1, q1.x, w0 * s1.x);
            v[k][5] = fmaf(w1, q1.y, w0 * s1.y);
            v[k][6] = fmaf(w1, q1.z, w0 * s1.z);
            v[k][7] = fmaf(w1, q1.w, w0 * s1.w);
        }
    } else {
        #pragma unroll
        for (int k = 0; k < ITERS; ++k) {
            const float* srow = sim + (size_t)prevI[k] * V + base;
            const float4 s0 = *(const float4*)(srow);
            const float4 s1 = *(const float4*)(srow + 4);
            v[k][0] = w0 * s0.x; v[k][1] = w0 * s0.y;
            v[k][2] = w0 * s0.z; v[k][3] = w0 * s0.w;
            v[k][4] = w0 * s1.x; v[k][5] = w0 * s1.y;
            v[k][6] = w0 * s1.z; v[k][7] = w0 * s1.w;
        }
    }

    // Per-row online softmax NLL; the 4 butterfly chains are independent (ILP).
    float acc = 0.0f;
    #pragma unroll
    for (int k = 0; k < ITERS; ++k) {
        float m = v[k][0];
        #pragma unroll
        for (int j = 1; j < 8; ++j) m = fmaxf(m, v[k][j]);
        #pragma unroll
        for (int off = 32; off >= 1; off >>= 1)
            m = fmaxf(m, __shfl_xor(m, off, 64));

        float s = 0.0f;
        #pragma unroll
        for (int j = 0; j < 8; ++j) s += __expf(v[k][j] - m);
        #pragma unroll
        for (int off = 32; off >= 1; off >>= 1)
            s += __shfl_xor(s, off, 64);

        acc += m + __logf(s) - lts[k];
    }

    // acc is wave-uniform after the butterflies
    __shared__ float part[WPB];
    if (lane == 0) part[wib] = acc;
    __syncthreads();
    if (threadIdx.x == 0)
        partial[blockIdx.x] = part[0] + part[1] + part[2] + part[3];
}

__global__ __launch_bounds__(256)
void nll_final(const float* __restrict__ partial, float* __restrict__ out)
{
    float s = 0.0f;
    for (int i = threadIdx.x; i < BLOCKS; i += 256) s += partial[i];
    #pragma unroll
    for (int off = 32; off >= 1; off >>= 1) s += __shfl_xor(s, off, 64);

    __shared__ float wsum[4];
    const int lane = threadIdx.x & 63;
    const int wib  = threadIdx.x >> 6;
    if (lane == 0) wsum[wib] = s;
    __syncthreads();
    if (threadIdx.x == 0)
        out[0] = wsum[0] + wsum[1] + wsum[2] + wsum[3]
               + (float)B * logf((float)V);   // nll0 = B * log(V)
}

extern "C" void kernel_launch(void* const* d_in, const int* in_sizes, int n_in,
                              void* d_out, int out_size, void* d_ws, size_t ws_size,
                              hipStream_t stream)
{
    const int*   seq  = (const int*)d_in[0];
    const float* sim  = (const float*)d_in[1];
    const float* pers = (const float*)d_in[2];
    const float* wts  = (const float*)d_in[3];
    float* partial = (float*)d_ws;            // 624 floats of scratch
    float* out     = (float*)d_out;

    nll_main<<<BLOCKS, 256, 0, stream>>>(seq, sim, pers, wts, partial);
    nll_final<<<1, 256, 0, stream>>>(partial, out);
}